// Round 10
// baseline (771.841 us; speedup 1.0000x reference)
//
#include <hip/hip_runtime.h>
#include <stdint.h>

#define B_TOK 8192
#define D_DIM 1024
#define H_DIM 4096
#define O_DIM 1024
#define E_NUM 8
#define K_TOP 2
#define NPAIR (B_TOK * K_TOP)   // 16384

typedef short bf16x8 __attribute__((ext_vector_type(8)));
typedef float f32x4 __attribute__((ext_vector_type(4)));

struct Hdr {
    int counts[8];
    int offsets[9];
    int total1, total2;
    int base1[9];   // 256-row tiles x H/256 n-tiles (GEMM1, 256x256)
    int base2[9];   // 128-row tiles x O/128 n-tiles (GEMM2, 128x128)
};

__device__ __forceinline__ unsigned short f2bf(float f) {
    union { float f; unsigned int u; } v; v.f = f;
    unsigned int u = v.u;
    unsigned int r = (u + 0x7fffu + ((u >> 16) & 1u)) >> 16;
    return (unsigned short)r;
}

__device__ __forceinline__ float bf2f(unsigned short s) {
    union { unsigned int u; float f; } v;
    v.u = ((unsigned int)s) << 16;
    return v.f;
}

// async global->LDS, 16B per lane; LDS side lands at (wave-uniform base) + lane*16
__device__ __forceinline__ void async16(const void* g, const void* l) {
    __builtin_amdgcn_global_load_lds(
        (__attribute__((address_space(1))) void*)(uintptr_t)g,
        (__attribute__((address_space(3))) void*)(uint32_t)(uintptr_t)l,
        16, 0, 0);
}

// ---------------- merged preprocessing: route + cvt_x + W-transpose -----------
// grid 16385 x 256:
//   bid == 0             : route (single block; FIRST so it hides under the rest)
//   1 <= bid <= 8192     : cvt_x      (x fp32 -> xb bf16, 4KB/block)
//   8193 <= bid < 16385  : tconv      (W1/W2 fp32 [R][C] -> bf16 [C][R], 128x64)
__global__ __launch_bounds__(256) void pre_kernel(
    const float* __restrict__ x, unsigned short* __restrict__ xb,
    const float* __restrict__ W1, const float* __restrict__ W2,
    unsigned short* __restrict__ o1, unsigned short* __restrict__ o2,
    const int* __restrict__ topk, const float* __restrict__ wts,
    Hdr* __restrict__ hdr, int* __restrict__ ptok, float* __restrict__ pgate) {

    __shared__ unsigned short tb[64 * 134];
    int bid = blockIdx.x;
    int tid = threadIdx.x;

    if (bid == 0) {
        // ---- route (256 threads = 4 waves, LDS counters) ----
        int* wcnt = (int*)tb;        // [4][8]
        int* wcur = wcnt + 32;       // [4][8]
        int w = tid >> 6;
        if ((tid & 63) < 8) wcnt[w * 8 + (tid & 63)] = 0;
        __syncthreads();
        for (int j = 0; j < 64; j++) {
            int e = topk[tid + j * 256];
            atomicAdd(&wcnt[w * 8 + e], 1);
        }
        __syncthreads();
        if (tid == 0) {
            int off = 0, t1 = 0, t2 = 0;
            for (int e = 0; e < 8; e++) {
                int c = 0;
                for (int w2 = 0; w2 < 4; w2++) {
                    wcur[w2 * 8 + e] = off + c;
                    c += wcnt[w2 * 8 + e];
                }
                hdr->counts[e] = c;
                hdr->offsets[e] = off;
                hdr->base1[e] = t1;
                hdr->base2[e] = t2;
                t1 += ((c + 255) >> 8) * (H_DIM / 256);   // 16 n-tiles (256x256)
                t2 += ((c + 127) >> 7) * (O_DIM / 128);   // 8 n-tiles (128x128)
                off += c;
            }
            hdr->offsets[8] = off;
            hdr->base1[8] = t1;
            hdr->base2[8] = t2;
            hdr->total1 = t1;
            hdr->total2 = t2;
        }
        __syncthreads();
        for (int j = 0; j < 64; j++) {
            int i = tid + j * 256;
            int e = topk[i];
            int pos = atomicAdd(&wcur[w * 8 + e], 1);
            ptok[pos] = i >> 1;
            pgate[pos] = wts[i];
        }
        return;
    }

    if (bid <= 8192) {
        // ---- cvt_x ----
        int i = ((bid - 1) * 256 + tid) * 4;
        float4 v = *(const float4*)(x + i);
        ushort4 o;
        o.x = f2bf(v.x); o.y = f2bf(v.y); o.z = f2bf(v.z); o.w = f2bf(v.w);
        *(ushort4*)(xb + i) = o;
        return;
    }

    // ---- tconv: 128(R) x 64(C) tiles, 256B-contiguous output chunks ----
    int bt = bid - 8193;
    int z = bt >> 9;             // 0..15
    int sub = bt & 511;
    int R, C;
    const float* ip;
    unsigned short* op;
    if (z < 8) {
        R = D_DIM; C = H_DIM;    // 8 x 64 tiles
        ip = W1 + (size_t)z * R * C;
        op = o1 + (size_t)z * R * C;
    } else {
        R = H_DIM; C = O_DIM;    // 32 x 16 tiles
        ip = W2 + (size_t)(z - 8) * R * C;
        op = o2 + (size_t)(z - 8) * R * C;
    }
    int tR = R >> 7;
    int r0 = (sub % tR) * 128;
    int c0 = (sub / tR) * 64;

    int rl = tid >> 4;           // 0..15
    int cg = (tid & 15) * 4;     // 0..60
#pragma unroll
    for (int p = 0; p < 8; p++) {
        int r = rl + p * 16;     // 0..127
        float4 v = *(const float4*)&ip[(size_t)(r0 + r) * C + c0 + cg];
        tb[(cg + 0) * 134 + r] = f2bf(v.x);
        tb[(cg + 1) * 134 + r] = f2bf(v.y);
        tb[(cg + 2) * 134 + r] = f2bf(v.z);
        tb[(cg + 3) * 134 + r] = f2bf(v.w);
    }
    __syncthreads();
    int r16 = (tid & 15) * 8;    // 16B per lane
#pragma unroll
    for (int i = 0; i < 4; i++) {
        int c = (tid >> 4) + i * 16;
        uint4 v = *(const uint4*)&tb[c * 134 + r16];
        *(uint4*)&op[(size_t)(c0 + c) * R + r0 + r16] = v;
    }
}

__global__ void ws_fail_kernel(float* out) { out[0] = 1.0e9f; }

// ---------------- GEMM1: 256x256 8-phase (counted vmcnt) ----------------
// Validated rounds 2/4/5/6/8. Round-9 lesson: the XCD-chunk decode needs the
// idx<chunk guard for an INJECTIVE tile map (idx in [chunk,grid/8) collided
// with the next XCD's range -> duplicate tiles; benign for stores, fatal for
// atomics, and always wasted work).

#define ASL(BUF, KH) ((BUF) * 32768 + (KH) * 16384)

#define STG_A(BUF, KH, KOFF) do { \
    async16(Ab + srcA[0] + (KOFF), smem + ASL(BUF, KH) + wu * 2048); \
    async16(Ab + srcA[1] + (KOFF), smem + ASL(BUF, KH) + wu * 2048 + 1024); } while (0)

#define STG_B(BUF, KH, KOFF) do { \
    async16(Bb + srcB[0] + (KOFF), smem + 65536 + ASL(BUF, KH) + wu * 2048); \
    async16(Bb + srcB[1] + (KOFF), smem + 65536 + ASL(BUF, KH) + wu * 2048 + 1024); } while (0)

#define VM6 asm volatile("s_waitcnt vmcnt(6)" ::: "memory")
#define VM0 asm volatile("s_waitcnt vmcnt(0)" ::: "memory")
#define NOPX ((void)0)

#define PHASE0(BUF, KH, STAGE, CKPT) do { \
    STAGE; \
    bq[0] = *(const bf16x8*)&smem[pBo[0] + ASL(BUF, KH)]; \
    bq[1] = *(const bf16x8*)&smem[pBo[1] + ASL(BUF, KH)]; \
    bq[2] = *(const bf16x8*)&smem[pBo[2] + ASL(BUF, KH)]; \
    bq[3] = *(const bf16x8*)&smem[pBo[3] + ASL(BUF, KH)]; \
    aq[0] = *(const bf16x8*)&smem[pAo[0] + ASL(BUF, KH)]; \
    aq[1] = *(const bf16x8*)&smem[pAo[1] + ASL(BUF, KH)]; \
    aq[2] = *(const bf16x8*)&smem[pAo[2] + ASL(BUF, KH)]; \
    aq[3] = *(const bf16x8*)&smem[pAo[3] + ASL(BUF, KH)]; \
    __builtin_amdgcn_s_barrier(); \
    asm volatile("s_waitcnt lgkmcnt(0)" ::: "memory"); \
    __builtin_amdgcn_s_setprio(1); \
    _Pragma("unroll") \
    for (int q_ = 0; q_ < 4; ++q_) { \
        _Pragma("unroll") \
        for (int n_ = 0; n_ < 4; ++n_) \
            acc[q_][n_] = __builtin_amdgcn_mfma_f32_16x16x32_bf16(aq[q_], bq[n_], acc[q_][n_], 0, 0, 0); \
    } \
    __builtin_amdgcn_s_setprio(0); \
    CKPT; \
    __builtin_amdgcn_s_barrier(); \
} while (0)

#define PHASE1(BUF, KH, STAGE, CKPT) do { \
    STAGE; \
    aq[0] = *(const bf16x8*)&smem[pAo[4] + ASL(BUF, KH)]; \
    aq[1] = *(const bf16x8*)&smem[pAo[5] + ASL(BUF, KH)]; \
    aq[2] = *(const bf16x8*)&smem[pAo[6] + ASL(BUF, KH)]; \
    aq[3] = *(const bf16x8*)&smem[pAo[7] + ASL(BUF, KH)]; \
    __builtin_amdgcn_s_barrier(); \
    asm volatile("s_waitcnt lgkmcnt(0)" ::: "memory"); \
    __builtin_amdgcn_s_setprio(1); \
    _Pragma("unroll") \
    for (int q_ = 0; q_ < 4; ++q_) { \
        _Pragma("unroll") \
        for (int n_ = 0; n_ < 4; ++n_) \
            acc[4 + q_][n_] = __builtin_amdgcn_mfma_f32_16x16x32_bf16(aq[q_], bq[n_], acc[4 + q_][n_], 0, 0, 0); \
    } \
    __builtin_amdgcn_s_setprio(0); \
    CKPT; \
    __builtin_amdgcn_s_barrier(); \
} while (0)

template <int KD, int N, bool GATHER>
__global__ __launch_bounds__(512, 2) void moe_gemm256_kernel(
    const unsigned short* __restrict__ A,
    const unsigned short* __restrict__ Bt,
    const float* __restrict__ bias,
    const Hdr* __restrict__ hdr,
    const int* __restrict__ ptok,
    unsigned short* __restrict__ outp) {

    extern __shared__ __align__(16) char smem[];
    constexpr int NT = KD / 64;
    constexpr int NI = NT / 2;
    static_assert(NT >= 4 && (NT % 2) == 0, "K-tile count");

    const int tid = threadIdx.x;
    const int lane = tid & 63;
    const int wv = tid >> 6;
    const int wu = __builtin_amdgcn_readfirstlane(wv);
    const int lr = lane & 15;
    const int lkg = lane >> 4;       // 0..3
    const int wr = wv >> 2;          // 0..1 (M)
    const int wc = wv & 3;           // 0..3 (N)

    const int total = hdr->total1;
    const int* tb = hdr->base1;

    int chunk = (total + 7) >> 3;
    int idx = blockIdx.x >> 3;
    if (idx >= chunk) return;                 // injective tile map (r9 fix)
    int seq = (blockIdx.x & 7) * chunk + idx;
    if (seq >= total) return;

    int e = 0;
#pragma unroll
    for (int j = 1; j < 8; j++)
        if (seq >= tb[j]) e = j;
    e = __builtin_amdgcn_readfirstlane(e);
    int lt = seq - tb[e];
    int cnt = hdr->counts[e], off = hdr->offsets[e];
    int MT = (cnt + 255) >> 8;
    int mtile = lt % MT, ntile = lt / MT;   // consecutive seq share the B panel
    int m0 = mtile * 256, n0 = ntile * 256;

    const char* Ab = (const char*)A;
    const char* Bb = (const char*)(Bt + (size_t)e * ((size_t)N * KD));

    // stage-source offsets: thread covers physical granules g = wv*128 + l*64 + lane
    uint32_t srcA[2], srcB[2];
#pragma unroll
    for (int l = 0; l < 2; ++l) {
        int g = wv * 128 + l * 64 + lane;
        int rp = g >> 2, cp = g & 3;
        int c = (cp - (rp >> 1)) & 3;       // inverse swizzle
        int q = off + m0 + rp;
        q = q > NPAIR - 1 ? NPAIR - 1 : q;
        uint32_t rowA = GATHER ? (uint32_t)ptok[q] : (uint32_t)q;
        srcA[l] = rowA * (uint32_t)(KD * 2) + (uint32_t)(c * 16);
        srcB[l] = (uint32_t)(n0 + rp) * (uint32_t)(KD * 2) + (uint32_t)(c * 16);
    }

    // fragment read offsets (swizzled): phys = r*64 + ((c + (r>>1))&3)*16
    uint32_t pAo[8], pBo[4];
#pragma unroll
    for (int mr = 0; mr < 8; ++mr) {
        int r = wr * 128 + mr * 16 + lr;
        pAo[mr] = (uint32_t)(r * 64 + ((lkg + (r >> 1)) & 3) * 16);
    }
#pragma unroll
    for (int nr = 0; nr < 4; ++nr) {
        int r = wc * 64 + nr * 16 + lr;
        pBo[nr] = (uint32_t)(65536 + r * 64 + ((lkg + (r >> 1)) & 3) * 16);
    }

    f32x4 acc[8][4];
#pragma unroll
    for (int i = 0; i < 8; ++i)
#pragma unroll
        for (int j = 0; j < 4; ++j)
            acc[i][j] = (f32x4){0.f, 0.f, 0.f, 0.f};
    bf16x8 aq[4], bq[4];

    // prologue: 7 half-tiles (kt0 complete, kt1 minus A.k1), full drain once
    STG_A(0, 0, 0u);   STG_B(0, 0, 0u);
    STG_A(0, 1, 64u);  STG_B(0, 1, 64u);
    STG_A(1, 0, 128u); STG_B(1, 0, 128u);
    STG_B(1, 1, 192u);
    VM0;
    __builtin_amdgcn_s_barrier();

    for (int it = 0; it < NI - 1; ++it) {
        const uint32_t kb = (uint32_t)it * 256u;
        PHASE0(0, 0, STG_A(1, 1, kb + 192u), NOPX);   // ph1
        PHASE1(0, 0, STG_B(0, 0, kb + 256u), NOPX);   // ph2
        PHASE0(0, 1, STG_A(0, 0, kb + 256u), NOPX);   // ph3
        PHASE1(0, 1, STG_B(0, 1, kb + 320u), VM6);    // ph4
        PHASE0(1, 0, STG_A(0, 1, kb + 320u), NOPX);   // ph5
        PHASE1(1, 0, STG_B(1, 0, kb + 384u), NOPX);   // ph6
        PHASE0(1, 1, STG_A(1, 0, kb + 384u), NOPX);   // ph7
        PHASE1(1, 1, STG_B(1, 1, kb + 448u), VM6);    // ph8
    }
    {   // peeled last iteration: only ph1 stages (kt NT-1 A.k1); drain at ph4
        const uint32_t kb = (uint32_t)(NI - 1) * 256u;
        PHASE0(0, 0, STG_A(1, 1, kb + 192u), NOPX);
        PHASE1(0, 0, NOPX, NOPX);
        PHASE0(0, 1, NOPX, NOPX);
        PHASE1(0, 1, NOPX, VM0);
        PHASE0(1, 0, NOPX, NOPX);
        PHASE1(1, 0, NOPX, NOPX);
        PHASE0(1, 1, NOPX, NOPX);
        PHASE1(1, 1, NOPX, NOPX);
    }

    // ---- epilogue: 2 passes (m-half = wr), LDS [128][264] ushorts ----
    // C/D layout: col = lane&15, row = (lane>>4)*4 + reg
    unsigned short* eb = (unsigned short*)smem;
    int rows_valid = cnt - m0;
    if (rows_valid > 256) rows_valid = 256;
#pragma unroll
    for (int pass = 0; pass < 2; ++pass) {
        __syncthreads();
        if (wr == pass) {
#pragma unroll
            for (int nr = 0; nr < 4; ++nr) {
                int n = wc * 64 + nr * 16 + lr;
                float bv = bias[(size_t)e * N + n0 + n];
#pragma unroll
                for (int mr = 0; mr < 8; ++mr) {
#pragma unroll
                    for (int r2 = 0; r2 < 4; ++r2) {
                        int ml = mr * 16 + lkg * 4 + r2;   // 0..127 within half
                        float v = acc[mr][nr][r2] + bv;
                        if (GATHER) v = v > 0.f ? v : 0.f;
                        eb[ml * 264 + n] = f2bf(v);
                    }
                }
            }
        }
        __syncthreads();
        int rv = rows_valid - pass * 128;
        if (rv > 128) rv = 128;
#pragma unroll
        for (int j = 0; j < 8; ++j) {
            int idx2 = j * 512 + tid;
            int row = idx2 >> 5;       // 0..127, 32 lanes per row
            int c16 = idx2 & 31;       // 16B units across 256 cols
            if (row < rv) {
                uint4 v = *(const uint4*)&eb[row * 264 + c16 * 8];
                *(uint4*)&outp[(size_t)(off + m0 + pass * 128 + row) * N + n0 + c16 * 8] = v;
            }
        }
    }
}

// ---------------- GEMM2: 128x128 2-phase + fused combine (atomic f32) ----------
// Epilogue: out[token] += gate * (acc + bias), token/gate staged in LDS.
// Requires the injective tile map (idx<chunk guard) — atomics are not
// idempotent under duplicate tiles (round-9 failure).
template <int K, int N>
__global__ __launch_bounds__(256, 4) void moe_gemm128_kernel(
    const unsigned short* __restrict__ A,
    const unsigned short* __restrict__ Bt,
    const float* __restrict__ bias,
    const Hdr* __restrict__ hdr,
    const int* __restrict__ ptok,
    const float* __restrict__ pgate,
    float* __restrict__ out) {

    __shared__ __align__(16) unsigned short smem[128 * 132];
    unsigned short* As = smem;
    unsigned short* Bs = smem + 128 * 64;

    const int tid = threadIdx.x;
    const int lane = tid & 63;
    const int wv = tid >> 6;
    const int wu = __builtin_amdgcn_readfirstlane(wv);
    const int wm = (wv & 1) * 64;
    const int wn = (wv >> 1) * 64;
    const int lr = lane & 15;
    const int lkg = lane >> 4;

    const int total = hdr->total2;
    const int* tb = hdr->base2;
    constexpr int NT = N / 128;

    int chunk = (total + 7) >> 3;
    int idx = blockIdx.x >> 3;
    if (idx >= chunk) return;                 // injective tile map (r9 fix)
    int seq = (blockIdx.x & 7) * chunk + idx;
    if (seq >= total) return;

    int e = 0;
#pragma unroll
    for (int j = 1; j < 8; j++)
        if (seq >= tb[j]) e = j;
    e = __builtin_amdgcn_readfirstlane(e);
    int lt = seq - tb[e];
    int cnt = hdr->counts[e], off = hdr->offsets[e];
    int MT = (cnt + 127) >> 7;

    // 8x8 supertile decode (m fastest within group -> consecutive blocks share B)
    int band = lt / (NT * 8);
    int r = lt - band * (NT * 8);
    int mrem = MT - band * 8;
    mrem = mrem > 8 ? 8 : mrem;
    int gsz = mrem * 8;
    int g = r / gsz;
    int rg = r - g * gsz;
    int gm = rg % mrem;
    int gn = rg / mrem;
    int mtile = band * 8 + gm;
    int ntile = g * 8 + gn;
    int m0 = mtile * 128, n0 = ntile * 128;

    const char* Ab = (const char*)A;
    const char* Bb = (const char*)(Bt + (size_t)e * ((size_t)N * K));
    uint32_t offA[4], offB[4];
#pragma unroll
    for (int i = 0; i < 4; i++) {
        int s = i * 256 + tid;
        int rr = s >> 3;
        int cl = (s & 7) ^ (rr & 7);
        int p = off + m0 + rr;
        p = p > NPAIR - 1 ? NPAIR - 1 : p;
        offA[i] = ((uint32_t)p * (uint32_t)K + (uint32_t)cl * 8u) * 2u;
        offB[i] = (((uint32_t)(n0 + rr)) * (uint32_t)K + (uint32_t)cl * 8u) * 2u;
    }

    f32x4 zero = {0.f, 0.f, 0.f, 0.f};
    f32x4 acc[4][4];
#pragma unroll
    for (int mt = 0; mt < 4; mt++)
#pragma unroll
        for (int nt = 0; nt < 4; nt++) acc[mt][nt] = zero;

    for (int k0 = 0; k0 < K; k0 += 64) {
#pragma unroll
        for (int i = 0; i < 4; i++) {
            async16(Ab + offA[i], &As[(i * 256 + wu * 64) * 8]);
            async16(Bb + offB[i], &Bs[(i * 256 + wu * 64) * 8]);
            offA[i] += 128;
            offB[i] += 128;
        }
        __syncthreads();
#pragma unroll
        for (int ks = 0; ks < 2; ks++) {
            bf16x8 af[4];
#pragma unroll
            for (int q = 0; q < 4; q++) {
                int ra = wm + q * 16 + lr;
                int ca = (ks * 4 + lkg) ^ (ra & 7);
                af[q] = *(const bf16x8*)&As[ra * 64 + ca * 8];
            }
#pragma unroll
            for (int nt = 0; nt < 4; nt++) {
                int rb = wn + nt * 16 + lr;
                int cb = (ks * 4 + lkg) ^ (rb & 7);
                bf16x8 bfr = *(const bf16x8*)&Bs[rb * 64 + cb * 8];
#pragma unroll
                for (int mt = 0; mt < 4; mt++)
                    acc[mt][nt] = __builtin_amdgcn_mfma_f32_16x16x32_bf16(
                        af[mt], bfr, acc[mt][nt], 0, 0, 0);
            }
        }
        __syncthreads();
    }

    // ---- fused epilogue: stage token/gate for the tile's 128 rows, then
    //      out[token] += gate * (acc + bias) via global atomics ----
    int rows_valid = cnt - m0;
    if (rows_valid > 128) rows_valid = 128;
    int* tokl = (int*)smem;                      // bytes [0,512)
    float* gatel = (float*)((char*)smem + 512);  // bytes [512,1024)
    if (tid < 128) {
        bool v = tid < rows_valid;
        int slot = off + m0 + tid;
        tokl[tid] = v ? ptok[slot] : -1;
        gatel[tid] = v ? pgate[slot] : 0.f;
    }
    __syncthreads();
#pragma unroll
    for (int nt = 0; nt < 4; nt++) {
        int n = wn + nt * 16 + lr;
        float bv = bias[(size_t)e * N + n0 + n];
#pragma unroll
        for (int mt = 0; mt < 4; mt++) {
#pragma unroll
            for (int r2 = 0; r2 < 4; r2++) {
                int m = wm + mt * 16 + lkg * 4 + r2;
                int t = tokl[m];
                if (t >= 0)
                    atomicAdd(&out[(size_t)t * N + n0 + n],
                              gatel[m] * (acc[mt][nt][r2] + bv));
            }
        }
    }
}

// ---------------- launch ----------------

extern "C" void kernel_launch(void* const* d_in, const int* in_sizes, int n_in,
                              void* d_out, int out_size, void* d_ws, size_t ws_size,
                              hipStream_t stream) {
    const float* x   = (const float*)d_in[0];
    const int* topk  = (const int*)d_in[1];
    const float* wts = (const float*)d_in[2];
    const float* W1  = (const float*)d_in[3];
    const float* b1  = (const float*)d_in[4];
    const float* W2  = (const float*)d_in[5];
    const float* b2  = (const float*)d_in[6];
    float* out = (float*)d_out;

    char* ws = (char*)d_ws;
    size_t off = 0;
    auto alloc = [&](size_t bytes) -> void* {
        void* p = ws + off;
        off += (bytes + 255) & ~(size_t)255;
        return p;
    };
    Hdr* hdr = (Hdr*)alloc(sizeof(Hdr));
    int* ptok = (int*)alloc((size_t)NPAIR * 4);
    float* pgate = (float*)alloc((size_t)NPAIR * 4);
    unsigned short* xb   = (unsigned short*)alloc((size_t)B_TOK * D_DIM * 2);
    unsigned short* W1bt = (unsigned short*)alloc((size_t)E_NUM * D_DIM * H_DIM * 2);
    unsigned short* W2bt = (unsigned short*)alloc((size_t)E_NUM * H_DIM * O_DIM * 2);
    unsigned short* hbuf = (unsigned short*)alloc((size_t)NPAIR * H_DIM * 2);

    if (off > ws_size) {
        hipMemsetAsync(d_out, 0, (size_t)out_size * sizeof(float), stream);
        ws_fail_kernel<<<1, 1, 0, stream>>>(out);
        return;
    }

    static int attr_done = 0;
    if (!attr_done) {
        (void)hipFuncSetAttribute(
            reinterpret_cast<const void*>(&moe_gemm256_kernel<D_DIM, H_DIM, true>),
            hipFuncAttributeMaxDynamicSharedMemorySize, 131072);
        attr_done = 1;
    }

    // out must be zeroed: GEMM2 accumulates into it atomically
    hipMemsetAsync(out, 0, (size_t)B_TOK * O_DIM * sizeof(float), stream);

    // merged preprocessing: route (1, first) + cvt_x (8192) + tconv (8192)
    pre_kernel<<<16385, 256, 0, stream>>>(x, xb, W1, W2, W1bt, W2bt,
                                          topk, wts, hdr, ptok, pgate);

    // GEMM1: 256^2 8-phase; tiles <= 72*16 = 1152
    moe_gemm256_kernel<D_DIM, H_DIM, true><<<1152, 512, 131072, stream>>>(
        xb, W1bt, b1, hdr, ptok, hbuf);
    // GEMM2: 128^2 2-phase + fused combine; tiles <= 135*8 = 1080
    moe_gemm128_kernel<H_DIM, O_DIM><<<1152, 256, 0, stream>>>(
        hbuf, W2bt, b2, hdr, ptok, pgate, out);
}

// Round 11
// 686.843 us; speedup vs baseline: 1.1238x; 1.1238x over previous
//
#include <hip/hip_runtime.h>
#include <stdint.h>

#define B_TOK 8192
#define D_DIM 1024
#define H_DIM 4096
#define O_DIM 1024
#define E_NUM 8
#define K_TOP 2
#define NPAIR (B_TOK * K_TOP)   // 16384

typedef short bf16x8 __attribute__((ext_vector_type(8)));
typedef float f32x4 __attribute__((ext_vector_type(4)));

struct Hdr {
    int counts[8];
    int offsets[9];
    int total1, total2;
    int base1[9];   // 256-row tiles x H/256 n-tiles (GEMM1, 256x256)
    int base2[9];   // 128-row tiles x O/128 n-tiles (GEMM2, 128x128)
};

__device__ __forceinline__ unsigned short f2bf(float f) {
    union { float f; unsigned int u; } v; v.f = f;
    unsigned int u = v.u;
    unsigned int r = (u + 0x7fffu + ((u >> 16) & 1u)) >> 16;
    return (unsigned short)r;
}

__device__ __forceinline__ float bf2f(unsigned short s) {
    union { unsigned int u; float f; } v;
    v.u = ((unsigned int)s) << 16;
    return v.f;
}

// async global->LDS, 16B per lane; LDS side lands at (wave-uniform base) + lane*16
__device__ __forceinline__ void async16(const void* g, const void* l) {
    __builtin_amdgcn_global_load_lds(
        (__attribute__((address_space(1))) void*)(uintptr_t)g,
        (__attribute__((address_space(3))) void*)(uint32_t)(uintptr_t)l,
        16, 0, 0);
}

// ---------------- merged preprocessing: route + cvt_x + W-transpose -----------
// grid 16385 x 256:
//   bid == 0             : route (single block; FIRST so it hides under the rest)
//   1 <= bid <= 8192     : cvt_x      (x fp32 -> xb bf16, 4KB/block)
//   8193 <= bid < 16385  : tconv      (W1/W2 fp32 [R][C] -> bf16 [C][R], 128x64)
__global__ __launch_bounds__(256) void pre_kernel(
    const float* __restrict__ x, unsigned short* __restrict__ xb,
    const float* __restrict__ W1, const float* __restrict__ W2,
    unsigned short* __restrict__ o1, unsigned short* __restrict__ o2,
    const int* __restrict__ topk, Hdr* __restrict__ hdr,
    int* __restrict__ ptok, int* __restrict__ pslot) {

    __shared__ unsigned short tb[64 * 134];
    int bid = blockIdx.x;
    int tid = threadIdx.x;

    if (bid == 0) {
        // ---- route (256 threads = 4 waves, LDS counters) ----
        int* wcnt = (int*)tb;        // [4][8]
        int* wcur = wcnt + 32;       // [4][8]
        int w = tid >> 6;
        if ((tid & 63) < 8) wcnt[w * 8 + (tid & 63)] = 0;
        __syncthreads();
        for (int j = 0; j < 64; j++) {
            int e = topk[tid + j * 256];
            atomicAdd(&wcnt[w * 8 + e], 1);
        }
        __syncthreads();
        if (tid == 0) {
            int off = 0, t1 = 0, t2 = 0;
            for (int e = 0; e < 8; e++) {
                int c = 0;
                for (int w2 = 0; w2 < 4; w2++) {
                    wcur[w2 * 8 + e] = off + c;
                    c += wcnt[w2 * 8 + e];
                }
                hdr->counts[e] = c;
                hdr->offsets[e] = off;
                hdr->base1[e] = t1;
                hdr->base2[e] = t2;
                t1 += ((c + 255) >> 8) * (H_DIM / 256);   // 16 n-tiles (256x256)
                t2 += ((c + 127) >> 7) * (O_DIM / 128);   // 8 n-tiles (128x128)
                off += c;
            }
            hdr->offsets[8] = off;
            hdr->base1[8] = t1;
            hdr->base2[8] = t2;
            hdr->total1 = t1;
            hdr->total2 = t2;
        }
        __syncthreads();
        for (int j = 0; j < 64; j++) {
            int i = tid + j * 256;
            int e = topk[i];
            int pos = atomicAdd(&wcur[w * 8 + e], 1);
            ptok[pos] = i >> 1;
            pslot[i] = pos;
        }
        return;
    }

    if (bid <= 8192) {
        // ---- cvt_x ----
        int i = ((bid - 1) * 256 + tid) * 4;
        float4 v = *(const float4*)(x + i);
        ushort4 o;
        o.x = f2bf(v.x); o.y = f2bf(v.y); o.z = f2bf(v.z); o.w = f2bf(v.w);
        *(ushort4*)(xb + i) = o;
        return;
    }

    // ---- tconv: 128(R) x 64(C) tiles, 256B-contiguous output chunks ----
    int bt = bid - 8193;
    int z = bt >> 9;             // 0..15
    int sub = bt & 511;
    int R, C;
    const float* ip;
    unsigned short* op;
    if (z < 8) {
        R = D_DIM; C = H_DIM;    // 8 x 64 tiles
        ip = W1 + (size_t)z * R * C;
        op = o1 + (size_t)z * R * C;
    } else {
        R = H_DIM; C = O_DIM;    // 32 x 16 tiles
        ip = W2 + (size_t)(z - 8) * R * C;
        op = o2 + (size_t)(z - 8) * R * C;
    }
    int tR = R >> 7;
    int r0 = (sub % tR) * 128;
    int c0 = (sub / tR) * 64;

    int rl = tid >> 4;           // 0..15
    int cg = (tid & 15) * 4;     // 0..60
#pragma unroll
    for (int p = 0; p < 8; p++) {
        int r = rl + p * 16;     // 0..127
        float4 v = *(const float4*)&ip[(size_t)(r0 + r) * C + c0 + cg];
        tb[(cg + 0) * 134 + r] = f2bf(v.x);
        tb[(cg + 1) * 134 + r] = f2bf(v.y);
        tb[(cg + 2) * 134 + r] = f2bf(v.z);
        tb[(cg + 3) * 134 + r] = f2bf(v.w);
    }
    __syncthreads();
    int r16 = (tid & 15) * 8;    // 16B per lane
#pragma unroll
    for (int i = 0; i < 4; i++) {
        int c = (tid >> 4) + i * 16;
        uint4 v = *(const uint4*)&tb[c * 134 + r16];
        *(uint4*)&op[(size_t)(c0 + c) * R + r0 + r16] = v;
    }
}

__global__ void ws_fail_kernel(float* out) { out[0] = 1.0e9f; }

// ---------------- GEMM1: 256x256 8-phase (counted vmcnt) ----------------
// Validated rounds 2/4/5/6/8. Dedupe guard (r9/r10): idx<chunk keeps the
// XCD-chunk tile map injective — without it ~12% of blocks recompute tiles
// owned by the next XCD (wasted CU time; fatal for atomic epilogues).

#define ASL(BUF, KH) ((BUF) * 32768 + (KH) * 16384)

#define STG_A(BUF, KH, KOFF) do { \
    async16(Ab + srcA[0] + (KOFF), smem + ASL(BUF, KH) + wu * 2048); \
    async16(Ab + srcA[1] + (KOFF), smem + ASL(BUF, KH) + wu * 2048 + 1024); } while (0)

#define STG_B(BUF, KH, KOFF) do { \
    async16(Bb + srcB[0] + (KOFF), smem + 65536 + ASL(BUF, KH) + wu * 2048); \
    async16(Bb + srcB[1] + (KOFF), smem + 65536 + ASL(BUF, KH) + wu * 2048 + 1024); } while (0)

#define VM6 asm volatile("s_waitcnt vmcnt(6)" ::: "memory")
#define VM0 asm volatile("s_waitcnt vmcnt(0)" ::: "memory")
#define NOPX ((void)0)

#define PHASE0(BUF, KH, STAGE, CKPT) do { \
    STAGE; \
    bq[0] = *(const bf16x8*)&smem[pBo[0] + ASL(BUF, KH)]; \
    bq[1] = *(const bf16x8*)&smem[pBo[1] + ASL(BUF, KH)]; \
    bq[2] = *(const bf16x8*)&smem[pBo[2] + ASL(BUF, KH)]; \
    bq[3] = *(const bf16x8*)&smem[pBo[3] + ASL(BUF, KH)]; \
    aq[0] = *(const bf16x8*)&smem[pAo[0] + ASL(BUF, KH)]; \
    aq[1] = *(const bf16x8*)&smem[pAo[1] + ASL(BUF, KH)]; \
    aq[2] = *(const bf16x8*)&smem[pAo[2] + ASL(BUF, KH)]; \
    aq[3] = *(const bf16x8*)&smem[pAo[3] + ASL(BUF, KH)]; \
    __builtin_amdgcn_s_barrier(); \
    asm volatile("s_waitcnt lgkmcnt(0)" ::: "memory"); \
    __builtin_amdgcn_s_setprio(1); \
    _Pragma("unroll") \
    for (int q_ = 0; q_ < 4; ++q_) { \
        _Pragma("unroll") \
        for (int n_ = 0; n_ < 4; ++n_) \
            acc[q_][n_] = __builtin_amdgcn_mfma_f32_16x16x32_bf16(aq[q_], bq[n_], acc[q_][n_], 0, 0, 0); \
    } \
    __builtin_amdgcn_s_setprio(0); \
    CKPT; \
    __builtin_amdgcn_s_barrier(); \
} while (0)

#define PHASE1(BUF, KH, STAGE, CKPT) do { \
    STAGE; \
    aq[0] = *(const bf16x8*)&smem[pAo[4] + ASL(BUF, KH)]; \
    aq[1] = *(const bf16x8*)&smem[pAo[5] + ASL(BUF, KH)]; \
    aq[2] = *(const bf16x8*)&smem[pAo[6] + ASL(BUF, KH)]; \
    aq[3] = *(const bf16x8*)&smem[pAo[7] + ASL(BUF, KH)]; \
    __builtin_amdgcn_s_barrier(); \
    asm volatile("s_waitcnt lgkmcnt(0)" ::: "memory"); \
    __builtin_amdgcn_s_setprio(1); \
    _Pragma("unroll") \
    for (int q_ = 0; q_ < 4; ++q_) { \
        _Pragma("unroll") \
        for (int n_ = 0; n_ < 4; ++n_) \
            acc[4 + q_][n_] = __builtin_amdgcn_mfma_f32_16x16x32_bf16(aq[q_], bq[n_], acc[4 + q_][n_], 0, 0, 0); \
    } \
    __builtin_amdgcn_s_setprio(0); \
    CKPT; \
    __builtin_amdgcn_s_barrier(); \
} while (0)

template <int KD, int N, bool GATHER>
__global__ __launch_bounds__(512, 2) void moe_gemm256_kernel(
    const unsigned short* __restrict__ A,
    const unsigned short* __restrict__ Bt,
    const float* __restrict__ bias,
    const Hdr* __restrict__ hdr,
    const int* __restrict__ ptok,
    unsigned short* __restrict__ outp) {

    extern __shared__ __align__(16) char smem[];
    constexpr int NT = KD / 64;
    constexpr int NI = NT / 2;
    static_assert(NT >= 4 && (NT % 2) == 0, "K-tile count");

    const int tid = threadIdx.x;
    const int lane = tid & 63;
    const int wv = tid >> 6;
    const int wu = __builtin_amdgcn_readfirstlane(wv);
    const int lr = lane & 15;
    const int lkg = lane >> 4;       // 0..3
    const int wr = wv >> 2;          // 0..1 (M)
    const int wc = wv & 3;           // 0..3 (N)

    const int total = hdr->total1;
    const int* tb = hdr->base1;

    int chunk = (total + 7) >> 3;
    int idx = blockIdx.x >> 3;
    if (idx >= chunk) return;                 // injective tile map (r9 fix)
    int seq = (blockIdx.x & 7) * chunk + idx;
    if (seq >= total) return;

    int e = 0;
#pragma unroll
    for (int j = 1; j < 8; j++)
        if (seq >= tb[j]) e = j;
    e = __builtin_amdgcn_readfirstlane(e);
    int lt = seq - tb[e];
    int cnt = hdr->counts[e], off = hdr->offsets[e];
    int MT = (cnt + 255) >> 8;
    int mtile = lt % MT, ntile = lt / MT;   // consecutive seq share the B panel
    int m0 = mtile * 256, n0 = ntile * 256;

    const char* Ab = (const char*)A;
    const char* Bb = (const char*)(Bt + (size_t)e * ((size_t)N * KD));

    // stage-source offsets: thread covers physical granules g = wv*128 + l*64 + lane
    uint32_t srcA[2], srcB[2];
#pragma unroll
    for (int l = 0; l < 2; ++l) {
        int g = wv * 128 + l * 64 + lane;
        int rp = g >> 2, cp = g & 3;
        int c = (cp - (rp >> 1)) & 3;       // inverse swizzle
        int q = off + m0 + rp;
        q = q > NPAIR - 1 ? NPAIR - 1 : q;
        uint32_t rowA = GATHER ? (uint32_t)ptok[q] : (uint32_t)q;
        srcA[l] = rowA * (uint32_t)(KD * 2) + (uint32_t)(c * 16);
        srcB[l] = (uint32_t)(n0 + rp) * (uint32_t)(KD * 2) + (uint32_t)(c * 16);
    }

    // fragment read offsets (swizzled): phys = r*64 + ((c + (r>>1))&3)*16
    uint32_t pAo[8], pBo[4];
#pragma unroll
    for (int mr = 0; mr < 8; ++mr) {
        int r = wr * 128 + mr * 16 + lr;
        pAo[mr] = (uint32_t)(r * 64 + ((lkg + (r >> 1)) & 3) * 16);
    }
#pragma unroll
    for (int nr = 0; nr < 4; ++nr) {
        int r = wc * 64 + nr * 16 + lr;
        pBo[nr] = (uint32_t)(65536 + r * 64 + ((lkg + (r >> 1)) & 3) * 16);
    }

    f32x4 acc[8][4];
#pragma unroll
    for (int i = 0; i < 8; ++i)
#pragma unroll
        for (int j = 0; j < 4; ++j)
            acc[i][j] = (f32x4){0.f, 0.f, 0.f, 0.f};
    bf16x8 aq[4], bq[4];

    // prologue: 7 half-tiles (kt0 complete, kt1 minus A.k1), full drain once
    STG_A(0, 0, 0u);   STG_B(0, 0, 0u);
    STG_A(0, 1, 64u);  STG_B(0, 1, 64u);
    STG_A(1, 0, 128u); STG_B(1, 0, 128u);
    STG_B(1, 1, 192u);
    VM0;
    __builtin_amdgcn_s_barrier();

    for (int it = 0; it < NI - 1; ++it) {
        const uint32_t kb = (uint32_t)it * 256u;
        PHASE0(0, 0, STG_A(1, 1, kb + 192u), NOPX);   // ph1
        PHASE1(0, 0, STG_B(0, 0, kb + 256u), NOPX);   // ph2
        PHASE0(0, 1, STG_A(0, 0, kb + 256u), NOPX);   // ph3
        PHASE1(0, 1, STG_B(0, 1, kb + 320u), VM6);    // ph4
        PHASE0(1, 0, STG_A(0, 1, kb + 320u), NOPX);   // ph5
        PHASE1(1, 0, STG_B(1, 0, kb + 384u), NOPX);   // ph6
        PHASE0(1, 1, STG_A(1, 0, kb + 384u), NOPX);   // ph7
        PHASE1(1, 1, STG_B(1, 1, kb + 448u), VM6);    // ph8
    }
    {   // peeled last iteration: only ph1 stages (kt NT-1 A.k1); drain at ph4
        const uint32_t kb = (uint32_t)(NI - 1) * 256u;
        PHASE0(0, 0, STG_A(1, 1, kb + 192u), NOPX);
        PHASE1(0, 0, NOPX, NOPX);
        PHASE0(0, 1, NOPX, NOPX);
        PHASE1(0, 1, NOPX, VM0);
        PHASE0(1, 0, NOPX, NOPX);
        PHASE1(1, 0, NOPX, NOPX);
        PHASE0(1, 1, NOPX, NOPX);
        PHASE1(1, 1, NOPX, NOPX);
    }

    // ---- epilogue: 2 passes (m-half = wr), LDS [128][264] ushorts ----
    // C/D layout: col = lane&15, row = (lane>>4)*4 + reg
    unsigned short* eb = (unsigned short*)smem;
    int rows_valid = cnt - m0;
    if (rows_valid > 256) rows_valid = 256;
#pragma unroll
    for (int pass = 0; pass < 2; ++pass) {
        __syncthreads();
        if (wr == pass) {
#pragma unroll
            for (int nr = 0; nr < 4; ++nr) {
                int n = wc * 64 + nr * 16 + lr;
                float bv = bias[(size_t)e * N + n0 + n];
#pragma unroll
                for (int mr = 0; mr < 8; ++mr) {
#pragma unroll
                    for (int r2 = 0; r2 < 4; ++r2) {
                        int ml = mr * 16 + lkg * 4 + r2;   // 0..127 within half
                        float v = acc[mr][nr][r2] + bv;
                        if (GATHER) v = v > 0.f ? v : 0.f;
                        eb[ml * 264 + n] = f2bf(v);
                    }
                }
            }
        }
        __syncthreads();
        int rv = rows_valid - pass * 128;
        if (rv > 128) rv = 128;
#pragma unroll
        for (int j = 0; j < 8; ++j) {
            int idx2 = j * 512 + tid;
            int row = idx2 >> 5;       // 0..127, 32 lanes per row
            int c16 = idx2 & 31;       // 16B units across 256 cols
            if (row < rv) {
                uint4 v = *(const uint4*)&eb[row * 264 + c16 * 8];
                *(uint4*)&outp[(size_t)(off + m0 + pass * 128 + row) * N + n0 + c16 * 8] = v;
            }
        }
    }
}

// ---------------- GEMM2: 128x128 2-phase, bf16 store (proven 198us) ----------
template <int K, int N, bool GATHER>
__global__ __launch_bounds__(256, 4) void moe_gemm128_kernel(
    const unsigned short* __restrict__ A,
    const unsigned short* __restrict__ Bt,
    const float* __restrict__ bias,
    const Hdr* __restrict__ hdr,
    const int* __restrict__ ptok,
    unsigned short* __restrict__ outp) {

    __shared__ __align__(16) unsigned short smem[128 * 132];
    unsigned short* As = smem;
    unsigned short* Bs = smem + 128 * 64;

    const int tid = threadIdx.x;
    const int lane = tid & 63;
    const int wv = tid >> 6;
    const int wu = __builtin_amdgcn_readfirstlane(wv);
    const int wm = (wv & 1) * 64;
    const int wn = (wv >> 1) * 64;
    const int lr = lane & 15;
    const int lkg = lane >> 4;

    const int total = hdr->total2;
    const int* tb = hdr->base2;
    constexpr int NT = N / 128;

    int chunk = (total + 7) >> 3;
    int idx = blockIdx.x >> 3;
    if (idx >= chunk) return;                 // injective tile map (r9 fix)
    int seq = (blockIdx.x & 7) * chunk + idx;
    if (seq >= total) return;

    int e = 0;
#pragma unroll
    for (int j = 1; j < 8; j++)
        if (seq >= tb[j]) e = j;
    e = __builtin_amdgcn_readfirstlane(e);
    int lt = seq - tb[e];
    int cnt = hdr->counts[e], off = hdr->offsets[e];
    int MT = (cnt + 127) >> 7;

    // 8x8 supertile decode (m fastest within group -> consecutive blocks share B)
    int band = lt / (NT * 8);
    int r = lt - band * (NT * 8);
    int mrem = MT - band * 8;
    mrem = mrem > 8 ? 8 : mrem;
    int gsz = mrem * 8;
    int g = r / gsz;
    int rg = r - g * gsz;
    int gm = rg % mrem;
    int gn = rg / mrem;
    int mtile = band * 8 + gm;
    int ntile = g * 8 + gn;
    int m0 = mtile * 128, n0 = ntile * 128;

    const char* Ab = (const char*)A;
    const char* Bb = (const char*)(Bt + (size_t)e * ((size_t)N * K));
    uint32_t offA[4], offB[4];
#pragma unroll
    for (int i = 0; i < 4; i++) {
        int s = i * 256 + tid;
        int rr = s >> 3;
        int cl = (s & 7) ^ (rr & 7);
        int p = off + m0 + rr;
        p = p > NPAIR - 1 ? NPAIR - 1 : p;
        uint32_t row = GATHER ? (uint32_t)ptok[p] : (uint32_t)p;
        offA[i] = (row * (uint32_t)K + (uint32_t)cl * 8u) * 2u;
        offB[i] = (((uint32_t)(n0 + rr)) * (uint32_t)K + (uint32_t)cl * 8u) * 2u;
    }

    f32x4 zero = {0.f, 0.f, 0.f, 0.f};
    f32x4 acc[4][4];
#pragma unroll
    for (int mt = 0; mt < 4; mt++)
#pragma unroll
        for (int nt = 0; nt < 4; nt++) acc[mt][nt] = zero;

    for (int k0 = 0; k0 < K; k0 += 64) {
#pragma unroll
        for (int i = 0; i < 4; i++) {
            async16(Ab + offA[i], &As[(i * 256 + wu * 64) * 8]);
            async16(Bb + offB[i], &Bs[(i * 256 + wu * 64) * 8]);
            offA[i] += 128;
            offB[i] += 128;
        }
        __syncthreads();
#pragma unroll
        for (int ks = 0; ks < 2; ks++) {
            bf16x8 af[4];
#pragma unroll
            for (int q = 0; q < 4; q++) {
                int ra = wm + q * 16 + lr;
                int ca = (ks * 4 + lkg) ^ (ra & 7);
                af[q] = *(const bf16x8*)&As[ra * 64 + ca * 8];
            }
#pragma unroll
            for (int nt = 0; nt < 4; nt++) {
                int rb = wn + nt * 16 + lr;
                int cb = (ks * 4 + lkg) ^ (rb & 7);
                bf16x8 bfr = *(const bf16x8*)&Bs[rb * 64 + cb * 8];
#pragma unroll
                for (int mt = 0; mt < 4; mt++)
                    acc[mt][nt] = __builtin_amdgcn_mfma_f32_16x16x32_bf16(
                        af[mt], bfr, acc[mt][nt], 0, 0, 0);
            }
        }
        __syncthreads();
    }

    // epilogue: C tile -> LDS (bf16, row stride 132), then coalesced stores
#pragma unroll
    for (int nt = 0; nt < 4; nt++) {
        int n = wn + nt * 16 + lr;
        float bv = bias[(size_t)e * N + n0 + n];
#pragma unroll
        for (int mt = 0; mt < 4; mt++) {
#pragma unroll
            for (int r2 = 0; r2 < 4; r2++) {
                int m = wm + mt * 16 + lkg * 4 + r2;
                float v = acc[mt][nt][r2] + bv;
                if (GATHER) v = v > 0.f ? v : 0.f;
                smem[m * 132 + n] = f2bf(v);
            }
        }
    }
    __syncthreads();
    int rows_valid = cnt - m0;
    if (rows_valid > 128) rows_valid = 128;
#pragma unroll
    for (int j = 0; j < 16; j++) {
        int idx2 = j * 256 + tid;
        int row = idx2 >> 5;
        int lc8 = idx2 & 31;
        if (row < rows_valid) {
            uint2 v = *(const uint2*)&smem[row * 132 + lc8 * 4];
            *(uint2*)&outp[(size_t)(off + m0 + row) * N + n0 + lc8 * 4] = v;
        }
    }
}

// out[tok] = g0 * oslot[pslot[2t]] + g1 * oslot[pslot[2t+1]]
__global__ void combine_kernel(const unsigned short* __restrict__ oslot,
                               const int* __restrict__ pslot,
                               const float* __restrict__ wts,
                               float* __restrict__ out) {
    int tok = blockIdx.x;
    int s0 = pslot[tok * 2], s1 = pslot[tok * 2 + 1];
    float g0 = wts[tok * 2], g1 = wts[tok * 2 + 1];
    int n = threadIdx.x * 4;
    ushort4 a = *(const ushort4*)&oslot[(size_t)s0 * O_DIM + n];
    ushort4 b = *(const ushort4*)&oslot[(size_t)s1 * O_DIM + n];
    float4 o;
    o.x = g0 * bf2f(a.x) + g1 * bf2f(b.x);
    o.y = g0 * bf2f(a.y) + g1 * bf2f(b.y);
    o.z = g0 * bf2f(a.z) + g1 * bf2f(b.z);
    o.w = g0 * bf2f(a.w) + g1 * bf2f(b.w);
    *(float4*)&out[(size_t)tok * O_DIM + n] = o;
}

// ---------------- launch ----------------

extern "C" void kernel_launch(void* const* d_in, const int* in_sizes, int n_in,
                              void* d_out, int out_size, void* d_ws, size_t ws_size,
                              hipStream_t stream) {
    const float* x   = (const float*)d_in[0];
    const int* topk  = (const int*)d_in[1];
    const float* wts = (const float*)d_in[2];
    const float* W1  = (const float*)d_in[3];
    const float* b1  = (const float*)d_in[4];
    const float* W2  = (const float*)d_in[5];
    const float* b2  = (const float*)d_in[6];
    float* out = (float*)d_out;

    char* ws = (char*)d_ws;
    size_t off = 0;
    auto alloc = [&](size_t bytes) -> void* {
        void* p = ws + off;
        off += (bytes + 255) & ~(size_t)255;
        return p;
    };
    Hdr* hdr = (Hdr*)alloc(sizeof(Hdr));
    int* ptok = (int*)alloc((size_t)NPAIR * 4);
    int* pslot = (int*)alloc((size_t)NPAIR * 4);
    unsigned short* xb   = (unsigned short*)alloc((size_t)B_TOK * D_DIM * 2);
    unsigned short* W1bt = (unsigned short*)alloc((size_t)E_NUM * D_DIM * H_DIM * 2);
    unsigned short* W2bt = (unsigned short*)alloc((size_t)E_NUM * H_DIM * O_DIM * 2);
    unsigned short* hbuf = (unsigned short*)alloc((size_t)NPAIR * H_DIM * 2);
    // oslot aliases W1bt (dead after GEMM1): NPAIR*O_DIM*2 = 33.5MB < 67MB
    unsigned short* oslot = W1bt;

    if (off > ws_size) {
        hipMemsetAsync(d_out, 0, (size_t)out_size * sizeof(float), stream);
        ws_fail_kernel<<<1, 1, 0, stream>>>(out);
        return;
    }

    static int attr_done = 0;
    if (!attr_done) {
        (void)hipFuncSetAttribute(
            reinterpret_cast<const void*>(&moe_gemm256_kernel<D_DIM, H_DIM, true>),
            hipFuncAttributeMaxDynamicSharedMemorySize, 131072);
        attr_done = 1;
    }

    // merged preprocessing: route (1, first) + cvt_x (8192) + tconv (8192)
    pre_kernel<<<16385, 256, 0, stream>>>(x, xb, W1, W2, W1bt, W2bt,
                                          topk, hdr, ptok, pslot);

    // GEMM1: 256^2 8-phase; tiles <= 72*16 = 1152
    moe_gemm256_kernel<D_DIM, H_DIM, true><<<1152, 512, 131072, stream>>>(
        xb, W1bt, b1, hdr, ptok, hbuf);
    // GEMM2: 128^2 2-phase; tiles <= 135*8 = 1080
    moe_gemm128_kernel<H_DIM, O_DIM, false><<<1152, 256, 0, stream>>>(
        hbuf, W2bt, b2, hdr, ptok, oslot);
    combine_kernel<<<B_TOK, 256, 0, stream>>>(oslot, pslot, wts, out);
}